// Round 3
// baseline (258.060 us; speedup 1.0000x reference)
//
#include <hip/hip_runtime.h>
#include <math.h>

#define KEYS 11
#define NSTACK 4
#define NB 16
#define HH 128
#define WW 128
#define HW (HH * WW)          // 16384 floats per slice
#define CHUNKS 4              // chunks per slice
#define CHUNK_F4 1024         // float4s per chunk (4096 floats)
#define NSLICE (NB * NSTACK * KEYS)   // 704
#define NPART (NSLICE * CHUNKS)       // 2816

// ws layout (float elements):
//   [0]           : block-completion counter (memset to 0 each launch)
//   [1024  + p]   : partial sum,  p in [0, 2816)
//   [8192  + p]   : partial vmax
//   [16384 + p]   : partial imax (as int)

__global__ __launch_bounds__(256) void kp_fused_kernel(
    const float* __restrict__ cp,    // (16, 4, 22, 128, 128)
    const float* __restrict__ heat,  // (16, 11, 128, 128)
    const float* __restrict__ lab,   // (16, 11, 11)
    float* __restrict__ ws,
    float* __restrict__ out)         // 128: heat_loss(64) then label_loss(64)
{
    const int bid   = blockIdx.x;     // slice*4 + chunk
    const int c     = bid & 3;
    const int slice = bid >> 2;       // bs*11 + k
    const int k  = slice % KEYS;
    const int bs = slice / KEYS;      // b*4 + s
    const int b  = bs >> 2;

    const float4* __restrict__ hm4 = (const float4*)(cp + ((size_t)(bs * (2 * KEYS) + k)) * HW);
    const float4* __restrict__ ht4 = (const float4*)(heat + ((size_t)(b * KEYS + k)) * HW);

    const int tid = threadIdx.x;
    float sum  = 0.0f;
    float vmax = -INFINITY;
    int   imax = 0;

    #pragma unroll
    for (int j = 0; j < 4; j++) {
        int i = c * CHUNK_F4 + tid + j * 256;   // float4 index within slice
        float4 a = hm4[i];
        float4 h = ht4[i];
        float d0 = a.x - h.x, d1 = a.y - h.y, d2 = a.z - h.z, d3 = a.w - h.w;
        sum += d0 * d0 + d1 * d1 + d2 * d2 + d3 * d3;
        int base = i * 4;                        // in-slice scalar index
        // strictly-greater keeps the first occurrence (indices ascend per thread)
        if (a.x > vmax) { vmax = a.x; imax = base;     }
        if (a.y > vmax) { vmax = a.y; imax = base + 1; }
        if (a.z > vmax) { vmax = a.z; imax = base + 2; }
        if (a.w > vmax) { vmax = a.w; imax = base + 3; }
    }

    // wave-64 reduction (sum + argmax, first-index tie break)
    #pragma unroll
    for (int off = 32; off > 0; off >>= 1) {
        float ov = __shfl_down(vmax, off);
        int   oi = __shfl_down(imax, off);
        float os = __shfl_down(sum,  off);
        sum += os;
        if (ov > vmax || (ov == vmax && oi < imax)) { vmax = ov; imax = oi; }
    }

    __shared__ float s_sum[4];
    __shared__ float s_v[4];
    __shared__ int   s_i[4];
    __shared__ int   s_last;
    const int wave = tid >> 6;
    if ((tid & 63) == 0) { s_sum[wave] = sum; s_v[wave] = vmax; s_i[wave] = imax; }
    __syncthreads();

    if (tid == 0) {
        #pragma unroll
        for (int w = 1; w < 4; w++) {
            sum += s_sum[w];
            if (s_v[w] > vmax || (s_v[w] == vmax && s_i[w] < imax)) {
                vmax = s_v[w]; imax = s_i[w];
            }
        }
        // agent-scope stores: visible across XCD L2s (G16 hazard)
        __hip_atomic_store(&ws[1024 + bid],  sum,  __ATOMIC_RELAXED, __HIP_MEMORY_SCOPE_AGENT);
        __hip_atomic_store(&ws[8192 + bid],  vmax, __ATOMIC_RELAXED, __HIP_MEMORY_SCOPE_AGENT);
        __hip_atomic_store(&((int*)ws)[16384 + bid], imax, __ATOMIC_RELAXED, __HIP_MEMORY_SCOPE_AGENT);
        __threadfence();   // release partials before signaling
        unsigned old = atomicAdd((unsigned*)ws, 1u);   // device-scope by default
        s_last = (old == NPART - 1) ? 1 : 0;
    }
    __syncthreads();
    if (s_last == 0) return;   // uniform per block

    // ---- last block: final reduction (all 2816 partials are globally visible) ----
    __threadfence();   // acquire
    __shared__ float sh[NSLICE];   // per-slice heat partial
    __shared__ float sl[NSLICE];   // per-slice label partial

    for (int t = tid; t < NSLICE; t += 256) {
        const int kk  = t % KEYS;
        const int bss = t / KEYS;
        const int bb  = bss >> 2;

        // combine 4 chunk partials in chunk order (preserves first-index tie break)
        float fsum  = 0.0f;
        float fvmax = -INFINITY;
        int   fimax = 0;
        #pragma unroll
        for (int cc = 0; cc < CHUNKS; cc++) {
            int p = t * CHUNKS + cc;
            float v = __hip_atomic_load(&ws[8192 + p], __ATOMIC_RELAXED, __HIP_MEMORY_SCOPE_AGENT);
            if (v > fvmax) {
                fvmax = v;
                fimax = __hip_atomic_load(&((int*)ws)[16384 + p], __ATOMIC_RELAXED, __HIP_MEMORY_SCOPE_AGENT);
            }
            fsum += __hip_atomic_load(&ws[1024 + p], __ATOMIC_RELAXED, __HIP_MEMORY_SCOPE_AGENT);
        }
        sh[t] = fsum;

        // label loss for this (b, s, k)
        const float* __restrict__ L = lab + (size_t)(bb * KEYS + kk) * 11;
        float gx = L[9], gy = L[10];
        float loss = 0.0f;
        if ((gx > 0.0f) && (gy > 0.0f) && (gx < (float)HH) && (gy < (float)WW)) {
            const float* __restrict__ lb =
                cp + ((size_t)(bss * (2 * KEYS) + KEYS + kk)) * HW;
            float xf = (float)(fimax / WW);   // x = index // m (m == 128)
            float yf = (float)(fimax % WW);   // y = index %  m
            float dx = gx + L[7] - xf - lb[7];
            float dy = gy + L[8] - yf - lb[8];
            loss = dx * dx + dy * dy;
            float cm = 1.0f - fvmax;
            loss += cm * cm;
            #pragma unroll
            for (int j = 0; j < 7; j++) {
                float d = lb[j] - L[j];
                loss += d * d;
            }
        }
        sl[t] = loss;
    }
    __syncthreads();

    if (tid < 64) {   // tid == bs
        float a = 0.0f, cl = 0.0f;
        #pragma unroll
        for (int kk = 0; kk < KEYS; kk++) {
            a  += sh[tid * KEYS + kk];
            cl += sl[tid * KEYS + kk];
        }
        out[tid]      = a;
        out[64 + tid] = cl;
    }
}

extern "C" void kernel_launch(void* const* d_in, const int* in_sizes, int n_in,
                              void* d_out, int out_size, void* d_ws, size_t ws_size,
                              hipStream_t stream) {
    const float* cp   = (const float*)d_in[0];
    const float* heat = (const float*)d_in[1];
    const float* lab  = (const float*)d_in[2];
    float* out = (float*)d_out;
    float* ws  = (float*)d_ws;

    // zero the completion counter (ws is re-poisoned to 0xAA before every launch)
    hipMemsetAsync(ws, 0, 4, stream);
    kp_fused_kernel<<<NPART, 256, 0, stream>>>(cp, heat, lab, ws, out);
}

// Round 4
// 135.042 us; speedup vs baseline: 1.9110x; 1.9110x over previous
//
#include <hip/hip_runtime.h>
#include <math.h>

#define KEYS 11
#define NSTACK 4
#define NB 16
#define HH 128
#define WW 128
#define HW (HH * WW)

__global__ void kp_zero_out(float* out) {
    out[threadIdx.x] = 0.0f;  // 128 output floats
}

__global__ __launch_bounds__(256) void kp_loss_kernel(
    const float* __restrict__ cp,    // (16, 4, 22, 128, 128)
    const float* __restrict__ heat,  // (16, 11, 128, 128)
    const float* __restrict__ lab,   // (16, 11, 11)
    float* __restrict__ out)         // 128: heat_loss(64) then label_loss(64)
{
    const int bid = blockIdx.x;          // b*S*K + s*K + k
    const int k  = bid % KEYS;
    const int bs = bid / KEYS;           // b*NSTACK + s
    const int s  = bs % NSTACK;
    const int b  = bs / NSTACK;

    const float* __restrict__ hm = cp + ((size_t)((b * NSTACK + s) * (2 * KEYS) + k)) * HW;
    const float* __restrict__ ht = heat + ((size_t)(b * KEYS + k)) * HW;

    const int tid = threadIdx.x;
    float sum  = 0.0f;
    float vmax = -INFINITY;
    int   imax = 0;

    const float4* __restrict__ hm4 = (const float4*)hm;
    const float4* __restrict__ ht4 = (const float4*)ht;

    #pragma unroll 4
    for (int i = tid; i < HW / 4; i += 256) {
        float4 a = hm4[i];
        float4 c = ht4[i];
        float d0 = a.x - c.x, d1 = a.y - c.y, d2 = a.z - c.z, d3 = a.w - c.w;
        sum += d0 * d0 + d1 * d1 + d2 * d2 + d3 * d3;
        int base = i * 4;
        // strictly-greater keeps first occurrence (indices increase per thread)
        if (a.x > vmax) { vmax = a.x; imax = base;     }
        if (a.y > vmax) { vmax = a.y; imax = base + 1; }
        if (a.z > vmax) { vmax = a.z; imax = base + 2; }
        if (a.w > vmax) { vmax = a.w; imax = base + 3; }
    }

    // wave-64 reduction (sum + argmax with first-index tie break)
    #pragma unroll
    for (int off = 32; off > 0; off >>= 1) {
        float ov = __shfl_down(vmax, off);
        int   oi = __shfl_down(imax, off);
        float os = __shfl_down(sum,  off);
        sum += os;
        if (ov > vmax || (ov == vmax && oi < imax)) { vmax = ov; imax = oi; }
    }

    __shared__ float s_sum[4];
    __shared__ float s_v[4];
    __shared__ int   s_i[4];
    const int wave = tid >> 6;
    if ((tid & 63) == 0) { s_sum[wave] = sum; s_v[wave] = vmax; s_i[wave] = imax; }
    __syncthreads();

    if (tid == 0) {
        #pragma unroll
        for (int w = 1; w < 4; w++) {
            sum += s_sum[w];
            if (s_v[w] > vmax || (s_v[w] == vmax && s_i[w] < imax)) {
                vmax = s_v[w]; imax = s_i[w];
            }
        }
        atomicAdd(&out[bs], sum);

        // ---- label loss for this (b, s, k) ----
        const float* __restrict__ lb = cp + ((size_t)((b * NSTACK + s) * (2 * KEYS) + KEYS + k)) * HW;
        const float* __restrict__ L  = lab + (size_t)(b * KEYS + k) * 11;
        float gx = L[9], gy = L[10];
        bool valid = (gx > 0.0f) && (gy > 0.0f) && (gx < (float)HH) && (gy < (float)WW);
        if (valid) {
            float xf = (float)(imax / WW);   // row (x = index // m, m == W == 128)
            float yf = (float)(imax % WW);   // col
            float dx = gx + L[7] - xf - lb[7];
            float dy = gy + L[8] - yf - lb[8];
            float loss = dx * dx + dy * dy;
            float cm = 1.0f - vmax;
            loss += cm * cm;
            #pragma unroll
            for (int j = 0; j < 7; j++) {
                float d = lb[j] - L[j];
                loss += d * d;
            }
            atomicAdd(&out[64 + bs], loss);
        }
    }
}

extern "C" void kernel_launch(void* const* d_in, const int* in_sizes, int n_in,
                              void* d_out, int out_size, void* d_ws, size_t ws_size,
                              hipStream_t stream) {
    const float* cp   = (const float*)d_in[0];
    const float* heat = (const float*)d_in[1];
    const float* lab  = (const float*)d_in[2];
    float* out = (float*)d_out;

    kp_zero_out<<<1, 128, 0, stream>>>(out);
    kp_loss_kernel<<<NB * NSTACK * KEYS, 256, 0, stream>>>(cp, heat, lab, out);
}